// Round 6
// baseline (456.342 us; speedup 1.0000x reference)
//
#include <hip/hip_runtime.h>
#include <hip/hip_bf16.h>

#define BATCH   4096
#define DIM     64
#define HID     256
#define TSTEPS  200
#define SROWS   16                 // samples per block (MFMA N)
#define NBLOCKS (BATCH / SROWS)    // 256 blocks = 1 per CU
#define NTH     512                // 8 waves, 2 per SIMD

#define HP  264   // shorts: h1s/h2s row stride ([sample][h])

// ws frag-slot layout (1 slot = 64 lanes x 16B = 1KB):
//   W2  : slots [0, 8192)        g=0..15, kk=0..7   u=(g*8+kk)*64+lane
//   W3  : slots [8192, 10240)    g=0..3             u=SLOT_W3+(g*8+kk)*64+lane
//   W31 : slots [10240, 18432)   g=0..15 (dt-scaled W3@W1)
//   vb31: float[256] at short-offset SLOT_END*8     (dt * b3@W1)
#define SLOT_W3   8192
#define SLOT_W31  10240
#define SLOT_END  18432

typedef __bf16 bf16_t;
typedef bf16_t bf16x8 __attribute__((ext_vector_type(8)));
typedef float  f32x4  __attribute__((ext_vector_type(4)));

__device__ __forceinline__ unsigned short f2bf(float f) {
    unsigned u = __builtin_bit_cast(unsigned, f);
    u += 0x7FFFu + ((u >> 16) & 1u);   // RNE
    return (unsigned short)(u >> 16);
}

#if __has_builtin(__builtin_amdgcn_cvt_pk_bf16_f32)
__device__ __forceinline__ unsigned pk2(float lo, float hi) {
    return __builtin_bit_cast(unsigned, __builtin_amdgcn_cvt_pk_bf16_f32(lo, hi));
}
#else
__device__ __forceinline__ unsigned pk2(float lo, float hi) {
    return (unsigned)f2bf(lo) | ((unsigned)f2bf(hi) << 16);
}
#endif

// ---------------------------------------------------------------------------
// Weight prep (unchanged from R5).
// sigma storage order for hidden dims: stored p = w*32+quad*8+mt*4+r <->
// logical pi(p) = w*32+mt*16+quad*4+r. K-sides contracting over a
// sigma-stored tensor use: elem j -> logical k = kk*32+(j>>2)*16+quad*4+(j&3).
// W31 = dt * (W3 @ W1); vb31 = dt * b3 @ W1.
// ---------------------------------------------------------------------------
__global__ void prep_weights(const float* __restrict__ W1,
                             const float* __restrict__ W2,
                             const float* __restrict__ W3,
                             const float* __restrict__ b3,
                             const float* __restrict__ tarr,
                             unsigned short* __restrict__ ws) {
    int u = blockIdx.x * blockDim.x + threadIdx.x;
    const float dt = tarr[1] - tarr[0];
    if (u < SLOT_W31) {
        const int lane = u & 63, l16 = lane & 15, quad = lane >> 4;
        const float* src; int ld, m, kk;
        if (u < SLOT_W3) {
            int r = u >> 6; kk = r & 7; int g = r >> 3;
            src = W2; ld = HID; m = g * 16 + l16;
        } else {
            int r = (u - SLOT_W3) >> 6; kk = r & 7; int g = r >> 3;
            src = W3; ld = DIM; m = g * 16 + l16;
        }
        unsigned short tmp[8] __attribute__((aligned(16)));
        #pragma unroll
        for (int j = 0; j < 8; ++j) {
            int k = kk * 32 + ((j >> 2) << 4) + quad * 4 + (j & 3);
            tmp[j] = f2bf(src[(size_t)k * ld + m]);
        }
        *(uint4*)(ws + (size_t)u * 8) = *(const uint4*)tmp;
    } else if (u < SLOT_END) {
        const int lane = u & 63, l16 = lane & 15, quad = lane >> 4;
        int r = (u - SLOT_W31) >> 6; int kk = r & 7; int g = r >> 3;
        int m = g * 16 + l16;
        float acc[8] = {0.f, 0.f, 0.f, 0.f, 0.f, 0.f, 0.f, 0.f};
        int kj[8];
        #pragma unroll
        for (int j = 0; j < 8; ++j)
            kj[j] = kk * 32 + ((j >> 2) << 4) + quad * 4 + (j & 3);
        for (int d = 0; d < DIM; ++d) {
            float w1v = W1[(size_t)d * HID + m];
            #pragma unroll
            for (int j = 0; j < 8; ++j)
                acc[j] = __builtin_fmaf(W3[(size_t)kj[j] * DIM + d], w1v, acc[j]);
        }
        unsigned short tmp[8] __attribute__((aligned(16)));
        #pragma unroll
        for (int j = 0; j < 8; ++j) tmp[j] = f2bf(dt * acc[j]);
        *(uint4*)(ws + (size_t)u * 8) = *(const uint4*)tmp;
    } else if (u < SLOT_END + HID) {
        int h = u - SLOT_END;
        float a = 0.f;
        for (int d = 0; d < DIM; ++d)
            a = __builtin_fmaf(b3[d], W1[(size_t)d * HID + h], a);
        ((float*)(ws + (size_t)SLOT_END * 8))[h] = dt * a;
    }
}

// ---------------------------------------------------------------------------
// Persistent ODE kernel, 2 phases/step (zb-state fusion, R5) with:
//  - 4 independent MFMA chains per GEMM (kk 0-3 / 4-7 split accumulators)
//    to halve dependent-MFMA chain depth (latency-exposure theory).
//  - own-slice-in-register: the sigma layout makes a wave's packed epilogue
//    uint4 EQUAL its own B-fragment bfr[w] for the next GEMM (same lane!).
//    Skip that ds_read (112 instead of 128 reads/step) and start the kk=w
//    chain with zero post-barrier LDS latency.
// ---------------------------------------------------------------------------
__global__ void __launch_bounds__(NTH, 2)
ode_kernel(const float* __restrict__ y0,
           const float* __restrict__ tarr,
           const float* __restrict__ W1,
           const float* __restrict__ b1,
           const float* __restrict__ b2,
           const float* __restrict__ b3,
           const unsigned short* __restrict__ wf,
           float* __restrict__ out) {
    __shared__ __align__(16) unsigned short h1s[SROWS * HP];
    __shared__ __align__(16) unsigned short h2s[SROWS * HP];

    const int tid  = threadIdx.x;
    const int w    = tid >> 6;        // wave 0..7
    const int lane = tid & 63;
    const int l16  = lane & 15;       // sample within tile
    const int quad = lane >> 4;
    const int b0   = blockIdx.x * SROWS;

    const float dt = tarr[1] - tarr[0];

    // --- resident weight fragments ---
    const bf16x8* wv = (const bf16x8*)wf;
    bf16x8 w2f[2][8], w31f[2][8], w3f[8];
    #pragma unroll
    for (int mt = 0; mt < 2; ++mt) {
        const int g = w * 2 + mt;
        #pragma unroll
        for (int kk = 0; kk < 8; ++kk) {
            w2f[mt][kk]  = wv[(g * 8 + kk) * 64 + lane];
            w31f[mt][kk] = wv[SLOT_W31 + (g * 8 + kk) * 64 + lane];
        }
    }
    if (w < 4)
        #pragma unroll
        for (int kk = 0; kk < 8; ++kk) w3f[kk] = wv[SLOT_W3 + (w * 8 + kk) * 64 + lane];

    // --- per-step constants in C/D layout ---
    f32x4 binit2[2], dtb31[2], binit3;
    const float* vb31 = (const float*)(wf + (size_t)SLOT_END * 8);
    #pragma unroll
    for (int mt = 0; mt < 2; ++mt)
        #pragma unroll
        for (int r = 0; r < 4; ++r) {
            binit2[mt][r] = b2[(w * 2 + mt) * 16 + quad * 4 + r];
            dtb31[mt][r]  = vb31[(w * 2 + mt) * 16 + quad * 4 + r];
        }

    // --- init y-state (waves 0-3) + t=0 output + y^T temp into h2s ---
    float yreg[4];
    float* outp = out;
    if (w < 4) {
        #pragma unroll
        for (int r = 0; r < 4; ++r) binit3[r] = b3[w * 16 + quad * 4 + r];
        outp = out + (size_t)(b0 + l16) * (TSTEPS * DIM) + w * 16 + quad * 4;
        float4 v = *(const float4*)&y0[(size_t)(b0 + l16) * DIM + w * 16 + quad * 4];
        yreg[0] = v.x; yreg[1] = v.y; yreg[2] = v.z; yreg[3] = v.w;
        uint2 p; p.x = pk2(v.x, v.y); p.y = pk2(v.z, v.w);
        *(uint2*)&h2s[l16 * HP + w * 16 + quad * 4] = p;   // y^T (logical), temp
        *(float4*)outp = v;
        outp += DIM;
    }
    __syncthreads();

    const unsigned short* h1base = &h1s[l16 * HP];
    const unsigned short* h2base = &h2s[l16 * HP];
    const int ep_off = l16 * HP + w * 32 + quad * 8;   // sigma epilogue slot

    bf16x8 h1own, h2own;   // own sigma-slice, doubles as bfr[w] next phase

    // --- init zb(0) = y0@W1 + b1 (one-time GEMM1) ---
    f32x4 zacc[2];
    {
        bf16x8 ybfr[2];
        #pragma unroll
        for (int kk = 0; kk < 2; ++kk)
            ybfr[kk] = *(const bf16x8*)&h2s[l16 * HP + kk * 32 + quad * 8];
        #pragma unroll
        for (int mt = 0; mt < 2; ++mt) {
            f32x4 a;
            #pragma unroll
            for (int r = 0; r < 4; ++r) a[r] = b1[(w * 2 + mt) * 16 + quad * 4 + r];
            #pragma unroll
            for (int kk = 0; kk < 2; ++kk) {
                unsigned short t8[8] __attribute__((aligned(16)));
                #pragma unroll
                for (int j = 0; j < 8; ++j)
                    t8[j] = f2bf(W1[(size_t)(kk * 32 + quad * 8 + j) * HID
                                    + (w * 2 + mt) * 16 + l16]);
                bf16x8 wf1 = *(const bf16x8*)t8;
                a = __builtin_amdgcn_mfma_f32_16x16x32_bf16(wf1, ybfr[kk], a, 0, 0, 0);
            }
            zacc[mt] = a;
        }
        uint4 p;
        p.x = pk2(zacc[0][0] > 0.f ? zacc[0][0] : 0.f, zacc[0][1] > 0.f ? zacc[0][1] : 0.f);
        p.y = pk2(zacc[0][2] > 0.f ? zacc[0][2] : 0.f, zacc[0][3] > 0.f ? zacc[0][3] : 0.f);
        p.z = pk2(zacc[1][0] > 0.f ? zacc[1][0] : 0.f, zacc[1][1] > 0.f ? zacc[1][1] : 0.f);
        p.w = pk2(zacc[1][2] > 0.f ? zacc[1][2] : 0.f, zacc[1][3] > 0.f ? zacc[1][3] : 0.f);
        *(uint4*)&h1s[ep_off] = p;
        h1own = __builtin_bit_cast(bf16x8, p);
    }
    __syncthreads();

    for (int t = 1; t < TSTEPS; ++t) {
        // ---- P-A: h2^T = relu(W2^T @ h1^T + b2), 4 chains ----
        {
            f32x4 acc[2]  = {binit2[0], binit2[1]};         // kk 0-3 chains
            f32x4 accX[2] = {{0.f,0.f,0.f,0.f}, {0.f,0.f,0.f,0.f}}; // kk 4-7
            bf16x8 bfr[8];
            #pragma unroll
            for (int kk = 0; kk < 8; ++kk) {
                if (kk == w) bfr[kk] = h1own;               // own slice: no read
                else bfr[kk] = *(const bf16x8*)&h1base[kk * 32 + quad * 8];
            }
            #pragma unroll
            for (int kk = 0; kk < 4; ++kk)
                #pragma unroll
                for (int mt = 0; mt < 2; ++mt) {
                    acc[mt] = __builtin_amdgcn_mfma_f32_16x16x32_bf16(
                        w2f[mt][kk], bfr[kk], acc[mt], 0, 0, 0);
                    accX[mt] = __builtin_amdgcn_mfma_f32_16x16x32_bf16(
                        w2f[mt][kk + 4], bfr[kk + 4], accX[mt], 0, 0, 0);
                }
            f32x4 s0 = acc[0] + accX[0];
            f32x4 s1 = acc[1] + accX[1];
            uint4 p;
            p.x = pk2(s0[0] > 0.f ? s0[0] : 0.f, s0[1] > 0.f ? s0[1] : 0.f);
            p.y = pk2(s0[2] > 0.f ? s0[2] : 0.f, s0[3] > 0.f ? s0[3] : 0.f);
            p.z = pk2(s1[0] > 0.f ? s1[0] : 0.f, s1[1] > 0.f ? s1[1] : 0.f);
            p.w = pk2(s1[2] > 0.f ? s1[2] : 0.f, s1[3] > 0.f ? s1[3] : 0.f);
            *(uint4*)&h2s[ep_off] = p;
            h2own = __builtin_bit_cast(bf16x8, p);
        }
        __syncthreads();

        // ---- P-B: zb += W31'^T @ h2^T + vb31; h1 = relu(zb);
        //           waves 0-3: y += dt*(W3^T @ h2^T + b3), store out.
        //           zacc = carried chain (kk 0-3), zpart = fresh chain
        //           seeded with dtb31 (kk 4-7): 4-deep chains. ----
        {
            bf16x8 bfr[8];
            #pragma unroll
            for (int kk = 0; kk < 8; ++kk) {
                if (kk == w) bfr[kk] = h2own;               // own slice: no read
                else bfr[kk] = *(const bf16x8*)&h2base[kk * 32 + quad * 8];
            }
            f32x4 zpart[2] = {dtb31[0], dtb31[1]};
            #pragma unroll
            for (int kk = 0; kk < 4; ++kk) {
                zacc[0] = __builtin_amdgcn_mfma_f32_16x16x32_bf16(
                    w31f[0][kk], bfr[kk], zacc[0], 0, 0, 0);
                zacc[1] = __builtin_amdgcn_mfma_f32_16x16x32_bf16(
                    w31f[1][kk], bfr[kk], zacc[1], 0, 0, 0);
                zpart[0] = __builtin_amdgcn_mfma_f32_16x16x32_bf16(
                    w31f[0][kk + 4], bfr[kk + 4], zpart[0], 0, 0, 0);
                zpart[1] = __builtin_amdgcn_mfma_f32_16x16x32_bf16(
                    w31f[1][kk + 4], bfr[kk + 4], zpart[1], 0, 0, 0);
            }
            if (w < 4) {
                f32x4 ya = binit3;
                f32x4 yb = {0.f, 0.f, 0.f, 0.f};
                #pragma unroll
                for (int k = 0; k < 4; ++k) {
                    ya = __builtin_amdgcn_mfma_f32_16x16x32_bf16(
                        w3f[k], bfr[k], ya, 0, 0, 0);
                    yb = __builtin_amdgcn_mfma_f32_16x16x32_bf16(
                        w3f[k + 4], bfr[k + 4], yb, 0, 0, 0);
                }
                f32x4 ys = ya + yb;
                #pragma unroll
                for (int r = 0; r < 4; ++r)
                    yreg[r] = __builtin_fmaf(dt, ys[r], yreg[r]);
                float4 ov; ov.x = yreg[0]; ov.y = yreg[1]; ov.z = yreg[2]; ov.w = yreg[3];
                *(float4*)outp = ov;
                outp += DIM;
            }
            zacc[0] += zpart[0];
            zacc[1] += zpart[1];
            uint4 p;
            p.x = pk2(zacc[0][0] > 0.f ? zacc[0][0] : 0.f, zacc[0][1] > 0.f ? zacc[0][1] : 0.f);
            p.y = pk2(zacc[0][2] > 0.f ? zacc[0][2] : 0.f, zacc[0][3] > 0.f ? zacc[0][3] : 0.f);
            p.z = pk2(zacc[1][0] > 0.f ? zacc[1][0] : 0.f, zacc[1][1] > 0.f ? zacc[1][1] : 0.f);
            p.w = pk2(zacc[1][2] > 0.f ? zacc[1][2] : 0.f, zacc[1][3] > 0.f ? zacc[1][3] : 0.f);
            *(uint4*)&h1s[ep_off] = p;
            h1own = __builtin_bit_cast(bf16x8, p);
        }
        __syncthreads();
    }
}

extern "C" void kernel_launch(void* const* d_in, const int* in_sizes, int n_in,
                              void* d_out, int out_size, void* d_ws, size_t ws_size,
                              hipStream_t stream) {
    const float* y0 = (const float*)d_in[0];
    const float* t  = (const float*)d_in[1];
    const float* W1 = (const float*)d_in[2];
    const float* b1 = (const float*)d_in[3];
    const float* W2 = (const float*)d_in[4];
    const float* b2 = (const float*)d_in[5];
    const float* W3 = (const float*)d_in[6];
    const float* b3 = (const float*)d_in[7];
    float* out = (float*)d_out;
    unsigned short* wf = (unsigned short*)d_ws;   // needs ~289 KiB

    prep_weights<<<73, 256, 0, stream>>>(W1, W2, W3, b3, t, wf);
    ode_kernel<<<NBLOCKS, NTH, 0, stream>>>(y0, t, W1, b1, b2, b3, wf, out);
}

// Round 7
// 376.047 us; speedup vs baseline: 1.2135x; 1.2135x over previous
//
#include <hip/hip_runtime.h>
#include <hip/hip_bf16.h>

#define BATCH   4096
#define DIM     64
#define HID     256
#define TSTEPS  200
#define SROWS   16                 // samples per block (MFMA N)
#define NBLOCKS (BATCH / SROWS)    // 256 blocks = 1 per CU
#define NTH     512                // 8 waves, 2 per SIMD

#define HP  264   // shorts: h1s/h2s row stride ([sample][h])

// ws frag-slot layout (1 slot = 64 lanes x 16B = 1KB):
//   W2  : slots [0, 8192)        g=0..15, j=0..7   u=(g*8+j)*64+lane
//   W3  : slots [8192, 10240)    g=0..3            u=SLOT_W3+(g*8+j)*64+lane
//   W31 : slots [10240, 18432)   g=0..15 (dt-scaled W3@W1)
//   vb31: float[256] at short-offset SLOT_END*8    (dt * b3@W1)
// K-ROTATION: slot j of tile g holds k-slice (j + rot(g)) & 7, where
// rot = g>>1 for W2/W31 (wave w owns tiles 2w,2w+1) and rot = g for W3.
// So in-kernel slot 0 is always the wave's OWN sigma-slice -> register.
#define SLOT_W3   8192
#define SLOT_W31  10240
#define SLOT_END  18432

typedef __bf16 bf16_t;
typedef bf16_t bf16x8 __attribute__((ext_vector_type(8)));
typedef float  f32x4  __attribute__((ext_vector_type(4)));

__device__ __forceinline__ unsigned short f2bf(float f) {
    unsigned u = __builtin_bit_cast(unsigned, f);
    u += 0x7FFFu + ((u >> 16) & 1u);   // RNE
    return (unsigned short)(u >> 16);
}

#if __has_builtin(__builtin_amdgcn_cvt_pk_bf16_f32)
__device__ __forceinline__ unsigned pk2(float lo, float hi) {
    return __builtin_bit_cast(unsigned, __builtin_amdgcn_cvt_pk_bf16_f32(lo, hi));
}
#else
__device__ __forceinline__ unsigned pk2(float lo, float hi) {
    return (unsigned)f2bf(lo) | ((unsigned)f2bf(hi) << 16);
}
#endif

// ---------------------------------------------------------------------------
// Weight prep.
// sigma storage order for hidden dims: stored p = w*32+quad*8+mt*4+r <->
// logical pi(p) = w*32+mt*16+quad*4+r. K-sides contracting over a
// sigma-stored tensor use: elem j -> logical k = ks*32+(j>>2)*16+quad*4+(j&3),
// where ks is the (rotated) k-slice for this slot.
// W31 = dt * (W3 @ W1); vb31 = dt * b3 @ W1.
// ---------------------------------------------------------------------------
__global__ void prep_weights(const float* __restrict__ W1,
                             const float* __restrict__ W2,
                             const float* __restrict__ W3,
                             const float* __restrict__ b3,
                             const float* __restrict__ tarr,
                             unsigned short* __restrict__ ws) {
    int u = blockIdx.x * blockDim.x + threadIdx.x;
    const float dt = tarr[1] - tarr[0];
    if (u < SLOT_W31) {
        const int lane = u & 63, l16 = lane & 15, quad = lane >> 4;
        const float* src; int ld, m, ks;
        if (u < SLOT_W3) {
            int r = u >> 6; int j = r & 7; int g = r >> 3;
            src = W2; ld = HID; m = g * 16 + l16;
            ks = (j + (g >> 1)) & 7;                    // rotate by wave = g>>1
        } else {
            int r = (u - SLOT_W3) >> 6; int j = r & 7; int g = r >> 3;
            src = W3; ld = DIM; m = g * 16 + l16;
            ks = (j + g) & 7;                           // rotate by wave = g
        }
        unsigned short tmp[8] __attribute__((aligned(16)));
        #pragma unroll
        for (int e = 0; e < 8; ++e) {
            int k = ks * 32 + ((e >> 2) << 4) + quad * 4 + (e & 3);
            tmp[e] = f2bf(src[(size_t)k * ld + m]);
        }
        *(uint4*)(ws + (size_t)u * 8) = *(const uint4*)tmp;
    } else if (u < SLOT_END) {
        const int lane = u & 63, l16 = lane & 15, quad = lane >> 4;
        int r = (u - SLOT_W31) >> 6; int j = r & 7; int g = r >> 3;
        int m = g * 16 + l16;
        int ks = (j + (g >> 1)) & 7;                    // rotate by wave = g>>1
        float acc[8] = {0.f, 0.f, 0.f, 0.f, 0.f, 0.f, 0.f, 0.f};
        int kj[8];
        #pragma unroll
        for (int e = 0; e < 8; ++e)
            kj[e] = ks * 32 + ((e >> 2) << 4) + quad * 4 + (e & 3);
        for (int d = 0; d < DIM; ++d) {
            float w1v = W1[(size_t)d * HID + m];
            #pragma unroll
            for (int e = 0; e < 8; ++e)
                acc[e] = __builtin_fmaf(W3[(size_t)kj[e] * DIM + d], w1v, acc[e]);
        }
        unsigned short tmp[8] __attribute__((aligned(16)));
        #pragma unroll
        for (int e = 0; e < 8; ++e) tmp[e] = f2bf(dt * acc[e]);
        *(uint4*)(ws + (size_t)u * 8) = *(const uint4*)tmp;
    } else if (u < SLOT_END + HID) {
        int h = u - SLOT_END;
        float a = 0.f;
        for (int d = 0; d < DIM; ++d)
            a = __builtin_fmaf(b3[d], W1[(size_t)d * HID + h], a);
        ((float*)(ws + (size_t)SLOT_END * 8))[h] = dt * a;
    }
}

// ---------------------------------------------------------------------------
// Persistent ODE kernel, 2 phases/step (zb-state fusion) + rotated
// own-slice: slot 0 of every weight tile is the wave's OWN sigma-slice,
// which equals the wave's packed epilogue uint4 (same lane!) -> kept in a
// register. Per phase: 7 ds_reads instead of 8, and the slot-0 MFMAs issue
// at phase start with zero LDS latency (attacks the 64-read round-robin
// return schedule that gates each phase).
// ---------------------------------------------------------------------------
__global__ void __launch_bounds__(NTH, 2)
ode_kernel(const float* __restrict__ y0,
           const float* __restrict__ tarr,
           const float* __restrict__ W1,
           const float* __restrict__ b1,
           const float* __restrict__ b2,
           const float* __restrict__ b3,
           const unsigned short* __restrict__ wf,
           float* __restrict__ out) {
    __shared__ __align__(16) unsigned short h1s[SROWS * HP];
    __shared__ __align__(16) unsigned short h2s[SROWS * HP];

    const int tid  = threadIdx.x;
    const int w    = tid >> 6;        // wave 0..7
    const int lane = tid & 63;
    const int l16  = lane & 15;       // sample within tile
    const int quad = lane >> 4;
    const int b0   = blockIdx.x * SROWS;

    const float dt = tarr[1] - tarr[0];

    // --- resident weight fragments (k-rotated slot order) ---
    const bf16x8* wv = (const bf16x8*)wf;
    bf16x8 w2f[2][8], w31f[2][8], w3f[8];
    #pragma unroll
    for (int mt = 0; mt < 2; ++mt) {
        const int g = w * 2 + mt;
        #pragma unroll
        for (int j = 0; j < 8; ++j) {
            w2f[mt][j]  = wv[(g * 8 + j) * 64 + lane];
            w31f[mt][j] = wv[SLOT_W31 + (g * 8 + j) * 64 + lane];
        }
    }
    if (w < 4)
        #pragma unroll
        for (int j = 0; j < 8; ++j) w3f[j] = wv[SLOT_W3 + (w * 8 + j) * 64 + lane];

    // --- per-step constants in C/D layout ---
    f32x4 binit2[2], dtb31[2], binit3;
    const float* vb31 = (const float*)(wf + (size_t)SLOT_END * 8);
    #pragma unroll
    for (int mt = 0; mt < 2; ++mt)
        #pragma unroll
        for (int r = 0; r < 4; ++r) {
            binit2[mt][r] = b2[(w * 2 + mt) * 16 + quad * 4 + r];
            dtb31[mt][r]  = vb31[(w * 2 + mt) * 16 + quad * 4 + r];
        }

    // --- rotated, loop-invariant read offsets (slot j -> k-slice (w+j)&7) ---
    int roff[8];
    #pragma unroll
    for (int j = 0; j < 8; ++j) roff[j] = ((w + j) & 7) * 32 + quad * 8;

    // --- init y-state (waves 0-3) + t=0 output + y^T temp into h2s ---
    float yreg[4];
    float* outp = out;
    if (w < 4) {
        #pragma unroll
        for (int r = 0; r < 4; ++r) binit3[r] = b3[w * 16 + quad * 4 + r];
        outp = out + (size_t)(b0 + l16) * (TSTEPS * DIM) + w * 16 + quad * 4;
        float4 v = *(const float4*)&y0[(size_t)(b0 + l16) * DIM + w * 16 + quad * 4];
        yreg[0] = v.x; yreg[1] = v.y; yreg[2] = v.z; yreg[3] = v.w;
        uint2 p; p.x = pk2(v.x, v.y); p.y = pk2(v.z, v.w);
        *(uint2*)&h2s[l16 * HP + w * 16 + quad * 4] = p;   // y^T (logical), temp
        *(float4*)outp = v;
        outp += DIM;
    }
    __syncthreads();

    const unsigned short* h1base = &h1s[l16 * HP];
    const unsigned short* h2base = &h2s[l16 * HP];
    const int ep_off = l16 * HP + w * 32 + quad * 8;   // sigma epilogue slot

    bf16x8 h1own, h2own;   // own sigma-slice = bfr[0] of the next phase

    // --- init zb(0) = y0@W1 + b1 (one-time GEMM1) ---
    f32x4 zacc[2];
    {
        bf16x8 ybfr[2];
        #pragma unroll
        for (int kk = 0; kk < 2; ++kk)
            ybfr[kk] = *(const bf16x8*)&h2s[l16 * HP + kk * 32 + quad * 8];
        #pragma unroll
        for (int mt = 0; mt < 2; ++mt) {
            f32x4 a;
            #pragma unroll
            for (int r = 0; r < 4; ++r) a[r] = b1[(w * 2 + mt) * 16 + quad * 4 + r];
            #pragma unroll
            for (int kk = 0; kk < 2; ++kk) {
                unsigned short t8[8] __attribute__((aligned(16)));
                #pragma unroll
                for (int j = 0; j < 8; ++j)
                    t8[j] = f2bf(W1[(size_t)(kk * 32 + quad * 8 + j) * HID
                                    + (w * 2 + mt) * 16 + l16]);
                bf16x8 wf1 = *(const bf16x8*)t8;
                a = __builtin_amdgcn_mfma_f32_16x16x32_bf16(wf1, ybfr[kk], a, 0, 0, 0);
            }
            zacc[mt] = a;
        }
        uint4 p;
        p.x = pk2(zacc[0][0] > 0.f ? zacc[0][0] : 0.f, zacc[0][1] > 0.f ? zacc[0][1] : 0.f);
        p.y = pk2(zacc[0][2] > 0.f ? zacc[0][2] : 0.f, zacc[0][3] > 0.f ? zacc[0][3] : 0.f);
        p.z = pk2(zacc[1][0] > 0.f ? zacc[1][0] : 0.f, zacc[1][1] > 0.f ? zacc[1][1] : 0.f);
        p.w = pk2(zacc[1][2] > 0.f ? zacc[1][2] : 0.f, zacc[1][3] > 0.f ? zacc[1][3] : 0.f);
        *(uint4*)&h1s[ep_off] = p;
        h1own = __builtin_bit_cast(bf16x8, p);
    }
    __syncthreads();

    for (int t = 1; t < TSTEPS; ++t) {
        // ---- P-A: h2^T = relu(W2^T @ h1^T + b2) ----
        // slot 0 = own slice (register), slots 1-7 = rotated ds_reads.
        {
            f32x4 acc[2] = {binit2[0], binit2[1]};
            bf16x8 bfr[8];
            bfr[0] = h1own;
            #pragma unroll
            for (int j = 1; j < 8; ++j)
                bfr[j] = *(const bf16x8*)&h1base[roff[j]];
            #pragma unroll
            for (int j = 0; j < 8; ++j)
                #pragma unroll
                for (int mt = 0; mt < 2; ++mt)
                    acc[mt] = __builtin_amdgcn_mfma_f32_16x16x32_bf16(
                        w2f[mt][j], bfr[j], acc[mt], 0, 0, 0);
            uint4 p;
            p.x = pk2(acc[0][0] > 0.f ? acc[0][0] : 0.f, acc[0][1] > 0.f ? acc[0][1] : 0.f);
            p.y = pk2(acc[0][2] > 0.f ? acc[0][2] : 0.f, acc[0][3] > 0.f ? acc[0][3] : 0.f);
            p.z = pk2(acc[1][0] > 0.f ? acc[1][0] : 0.f, acc[1][1] > 0.f ? acc[1][1] : 0.f);
            p.w = pk2(acc[1][2] > 0.f ? acc[1][2] : 0.f, acc[1][3] > 0.f ? acc[1][3] : 0.f);
            *(uint4*)&h2s[ep_off] = p;
            h2own = __builtin_bit_cast(bf16x8, p);
        }
        __syncthreads();

        // ---- P-B: zb += W31'^T @ h2^T + vb31; h1 = relu(zb);
        //           waves 0-3: y += dt*(W3^T @ h2^T + b3), store out ----
        {
            bf16x8 bfr[8];
            bfr[0] = h2own;
            #pragma unroll
            for (int j = 1; j < 8; ++j)
                bfr[j] = *(const bf16x8*)&h2base[roff[j]];
            #pragma unroll
            for (int j = 0; j < 8; ++j) {
                zacc[0] = __builtin_amdgcn_mfma_f32_16x16x32_bf16(
                    w31f[0][j], bfr[j], zacc[0], 0, 0, 0);
                zacc[1] = __builtin_amdgcn_mfma_f32_16x16x32_bf16(
                    w31f[1][j], bfr[j], zacc[1], 0, 0, 0);
            }
            if (w < 4) {
                f32x4 ya = binit3;
                f32x4 yb = {0.f, 0.f, 0.f, 0.f};
                #pragma unroll
                for (int k = 0; k < 4; ++k) {
                    ya = __builtin_amdgcn_mfma_f32_16x16x32_bf16(
                        w3f[k], bfr[k], ya, 0, 0, 0);
                    yb = __builtin_amdgcn_mfma_f32_16x16x32_bf16(
                        w3f[k + 4], bfr[k + 4], yb, 0, 0, 0);
                }
                f32x4 ys = ya + yb;
                #pragma unroll
                for (int r = 0; r < 4; ++r)
                    yreg[r] = __builtin_fmaf(dt, ys[r], yreg[r]);
                float4 ov; ov.x = yreg[0]; ov.y = yreg[1]; ov.z = yreg[2]; ov.w = yreg[3];
                *(float4*)outp = ov;
                outp += DIM;
            }
            zacc[0] += dtb31[0];
            zacc[1] += dtb31[1];
            uint4 p;
            p.x = pk2(zacc[0][0] > 0.f ? zacc[0][0] : 0.f, zacc[0][1] > 0.f ? zacc[0][1] : 0.f);
            p.y = pk2(zacc[0][2] > 0.f ? zacc[0][2] : 0.f, zacc[0][3] > 0.f ? zacc[0][3] : 0.f);
            p.z = pk2(zacc[1][0] > 0.f ? zacc[1][0] : 0.f, zacc[1][1] > 0.f ? zacc[1][1] : 0.f);
            p.w = pk2(zacc[1][2] > 0.f ? zacc[1][2] : 0.f, zacc[1][3] > 0.f ? zacc[1][3] : 0.f);
            *(uint4*)&h1s[ep_off] = p;
            h1own = __builtin_bit_cast(bf16x8, p);
        }
        __syncthreads();
    }
}

extern "C" void kernel_launch(void* const* d_in, const int* in_sizes, int n_in,
                              void* d_out, int out_size, void* d_ws, size_t ws_size,
                              hipStream_t stream) {
    const float* y0 = (const float*)d_in[0];
    const float* t  = (const float*)d_in[1];
    const float* W1 = (const float*)d_in[2];
    const float* b1 = (const float*)d_in[3];
    const float* W2 = (const float*)d_in[4];
    const float* b2 = (const float*)d_in[5];
    const float* W3 = (const float*)d_in[6];
    const float* b3 = (const float*)d_in[7];
    float* out = (float*)d_out;
    unsigned short* wf = (unsigned short*)d_ws;   // needs ~289 KiB

    prep_weights<<<73, 256, 0, stream>>>(W1, W2, W3, b3, t, wf);
    ode_kernel<<<NBLOCKS, NTH, 0, stream>>>(y0, t, W1, b1, b2, b3, wf, out);
}